// Round 1
// baseline (1097.674 us; speedup 1.0000x reference)
//
#include <hip/hip_runtime.h>

#define DD 64

// ---------------------------------------------------------------------------
// rel_ctx[d] = mean over R rows of relation_embeddings[:, d]
__global__ void k_relctx(const float* __restrict__ rel, int R, float* __restrict__ ctx) {
    int d = threadIdx.x;
    if (d < DD) {
        float s = 0.f;
        for (int r = 0; r < R; ++r) s += rel[r * DD + d];
        ctx[d] = s / (float)R;
    }
}

// ---------------------------------------------------------------------------
// Edge scatter: one wave per edge, lane = dim. Coalesced 256B atomic bursts.
__global__ __launch_bounds__(256)
void k_edges(const int* __restrict__ src, const int* __restrict__ dst,
             const int* __restrict__ etype, const float* __restrict__ rel,
             float* __restrict__ sum, int* __restrict__ deg, int* __restrict__ nbr,
             int E) {
    int lane = threadIdx.x & 63;
    int wib  = threadIdx.x >> 6;
    int wpb  = blockDim.x >> 6;
    int wid  = blockIdx.x * wpb + wib;
    int nw   = gridDim.x * wpb;
    for (int e = wid; e < E; e += nw) {
        int s = src[e];
        int d = dst[e];
        int t = etype[e];
        float r = rel[t * DD + lane];
        atomicAdd(&sum[s * DD + lane], r);
        if (s != d) {
            atomicAdd(&sum[d * DD + lane], r);
            if (lane == 0) {
                atomicAdd(&deg[s], 1);
                atomicAdd(&deg[d], 1);
                atomicAdd(&nbr[s], 1);
                atomicAdd(&nbr[d], 1);
            }
        } else {
            if (lane == 0) atomicAdd(&deg[s], 1);
        }
    }
}

// ---------------------------------------------------------------------------
// Per-node MLP. MODE 0: nodes with has_nbr (branch b weights) + deg==0 ctx
// write-out. MODE 1: nodes with deg>0 && !has_nbr (branch a weights).
// One wave per node; weights staged transposed in LDS (conflict-free reads).
template <int MODE>
__global__ __launch_bounds__(256)
void k_nodes(const float* __restrict__ sum, const int* __restrict__ deg,
             const int* __restrict__ nbr, const float* __restrict__ ctx,
             const float* __restrict__ w1, const float* __restrict__ b1,
             const float* __restrict__ w2, const float* __restrict__ b2,
             const float* __restrict__ strength,
             float* __restrict__ out, int N) {
    __shared__ float w1t[128 * 64];   // [k][j] = w1[j][k]   (32 KB)
    __shared__ float w2t[64 * 64];    // [k][j] = w2[j][k]   (16 KB)
    __shared__ float b1s[64], b2s[64], ctx_s[64];
    __shared__ float xbuf[4][128];
    __shared__ float hbuf[4][64];

    for (int i = threadIdx.x; i < 128 * 64; i += blockDim.x) {
        int j = i >> 7, k = i & 127;        // i = j*128 + k
        w1t[k * 64 + j] = w1[i];
    }
    for (int i = threadIdx.x; i < 64 * 64; i += blockDim.x) {
        int j = i >> 6, k = i & 63;         // i = j*64 + k
        w2t[k * 64 + j] = w2[i];
    }
    if (threadIdx.x < 64) {
        b1s[threadIdx.x]   = b1[threadIdx.x];
        b2s[threadIdx.x]   = b2[threadIdx.x];
        ctx_s[threadIdx.x] = ctx[threadIdx.x];
    }
    __syncthreads();

    float s = fminf(fmaxf(strength[0], 0.f), 0.3f);

    int lane = threadIdx.x & 63;
    int w    = threadIdx.x >> 6;
    int wpb  = blockDim.x >> 6;
    int stride = gridDim.x * wpb;
    for (int n = blockIdx.x * wpb + w; n < N; n += stride) {
        int dg = deg[n];
        if (MODE == 0) {
            if (dg == 0) { out[n * DD + lane] = ctx_s[lane]; continue; }
            if (nbr[n] == 0) continue;          // branch-a node: other kernel
        } else {
            if (dg == 0 || nbr[n] != 0) continue;
        }
        float f = sum[n * DD + lane] / (float)dg;
        xbuf[w][lane]      = f;
        xbuf[w][64 + lane] = (MODE == 0) ? f : ctx_s[lane];
        // layer 1: h[j] = relu(sum_k x[k] * w1[j][k] + b1[j])
        float h = b1s[lane];
        #pragma unroll 8
        for (int k = 0; k < 128; ++k)
            h = fmaf(xbuf[w][k], w1t[k * 64 + lane], h);
        h = fmaxf(h, 0.f);
        hbuf[w][lane] = h;
        // layer 2
        float o = b2s[lane];
        #pragma unroll 8
        for (int k = 0; k < 64; ++k)
            o = fmaf(hbuf[w][k], w2t[k * 64 + lane], o);
        out[n * DD + lane] = (1.f - s) * f + s * o;
    }
}

// ---------------------------------------------------------------------------
extern "C" void kernel_launch(void* const* d_in, const int* in_sizes, int n_in,
                              void* d_out, int out_size, void* d_ws, size_t ws_size,
                              hipStream_t stream) {
    const int*   edge_index = (const int*)d_in[0];     // [2, E]
    const int*   etype      = (const int*)d_in[1];     // [E]
    const float* rel        = (const float*)d_in[2];   // [R, 64]
    const float* w1a        = (const float*)d_in[3];
    const float* b1a        = (const float*)d_in[4];
    const float* w2a        = (const float*)d_in[5];
    const float* b2a        = (const float*)d_in[6];
    const float* w1b        = (const float*)d_in[7];
    const float* b1b        = (const float*)d_in[8];
    const float* w2b        = (const float*)d_in[9];
    const float* b2b        = (const float*)d_in[10];
    const float* strength   = (const float*)d_in[11];

    int E = in_sizes[0] / 2;
    int R = in_sizes[2] / DD;
    int N = out_size / DD;

    float* out = (float*)d_out;
    char*  ws  = (char*)d_ws;
    float* sum = (float*)ws;                               // N*64 f32
    int*   deg = (int*)(ws + (size_t)N * DD * sizeof(float));
    int*   nbr = deg + N;
    float* ctx = (float*)(nbr + N);                        // 64 f32

    size_t zbytes = (size_t)N * DD * sizeof(float) + 2 * (size_t)N * sizeof(int);
    hipMemsetAsync(ws, 0, zbytes, stream);

    k_relctx<<<1, 64, 0, stream>>>(rel, R, ctx);

    k_edges<<<4096, 256, 0, stream>>>(edge_index, edge_index + E, etype, rel,
                                      sum, deg, nbr, E);

    // branch b (has_nbr) — covers ~all nodes, also writes deg==0 fallback
    k_nodes<0><<<1024, 256, 0, stream>>>(sum, deg, nbr, ctx,
                                         w1b, b1b, w2b, b2b, strength, out, N);
    // branch a (deg>0 && !has_nbr) — rare nodes
    k_nodes<1><<<1024, 256, 0, stream>>>(sum, deg, nbr, ctx,
                                         w1a, b1a, w2a, b2a, strength, out, N);
}

// Round 2
// 691.539 us; speedup vs baseline: 1.5873x; 1.5873x over previous
//
#include <hip/hip_runtime.h>

#define DD 64

// ---------------------------------------------------------------------------
// rel_ctx[d] = mean over R rows. 8 waves, each sums rows w::8, LDS reduce.
__global__ __launch_bounds__(512)
void k_relctx(const float* __restrict__ rel, int R, float* __restrict__ ctx) {
    __shared__ float part[8][DD];
    int d = threadIdx.x & 63;
    int w = threadIdx.x >> 6;
    float s = 0.f;
    for (int r = w; r < R; r += 8) s += rel[r * DD + d];
    part[w][d] = s;
    __syncthreads();
    if (threadIdx.x < DD) {
        float t = 0.f;
        #pragma unroll
        for (int i = 0; i < 8; ++i) t += part[i][threadIdx.x];
        ctx[threadIdx.x] = t / (float)R;
    }
}

// ---------------------------------------------------------------------------
// Pass 1: per-node incidence counts. Entry rule (matches reference):
//   src side: always counts (deg & sum), self-flag if src==dst
//   dst side: only when src!=dst
__global__ __launch_bounds__(256)
void k_count(const int* __restrict__ src, const int* __restrict__ dst,
             int* __restrict__ cnt, int E) {
    int i = blockIdx.x * blockDim.x + threadIdx.x;
    int stride = gridDim.x * blockDim.x;
    for (; i < E; i += stride) {
        int s = src[i], d = dst[i];
        atomicAdd(&cnt[s], 1);
        if (s != d) atomicAdd(&cnt[d], 1);
    }
}

// ---------------------------------------------------------------------------
// Single-block exclusive scan over N counts -> off[0..N], cur[0..N-1]
__global__ __launch_bounds__(1024)
void k_scan(const int* __restrict__ cnt, int* __restrict__ off,
            int* __restrict__ cur, int N) {
    __shared__ int sh[1024];
    int t = threadIdx.x;
    int chunk = (N + 1023) / 1024;
    int lo = t * chunk, hi = min(lo + chunk, N);
    int s = 0;
    for (int i = lo; i < hi; ++i) s += cnt[i];
    sh[t] = s;
    __syncthreads();
    for (int d = 1; d < 1024; d <<= 1) {
        int v = (t >= d) ? sh[t - d] : 0;
        __syncthreads();
        sh[t] += v;
        __syncthreads();
    }
    int run = sh[t] - s;   // exclusive prefix
    for (int i = lo; i < hi; ++i) {
        off[i] = run; cur[i] = run;
        run += cnt[i];
    }
    if (t == 1023) off[N] = sh[1023];
}

// ---------------------------------------------------------------------------
// Pass 2: place incidences. bucket entry u16 = etype | (self << 15)
__global__ __launch_bounds__(256)
void k_place(const int* __restrict__ src, const int* __restrict__ dst,
             const int* __restrict__ etype, int* __restrict__ cur,
             unsigned short* __restrict__ bucket, int E) {
    int i = blockIdx.x * blockDim.x + threadIdx.x;
    int stride = gridDim.x * blockDim.x;
    for (; i < E; i += stride) {
        int s = src[i], d = dst[i];
        unsigned short t = (unsigned short)etype[i];
        if (s != d) {
            int p = atomicAdd(&cur[s], 1);
            bucket[p] = t;
            int q = atomicAdd(&cur[d], 1);
            bucket[q] = t;
        } else {
            int p = atomicAdd(&cur[s], 1);
            bucket[p] = t | 0x8000;
        }
    }
}

// ---------------------------------------------------------------------------
// Fused gather + branch-b MLP. One wave per node, lane = dim.
//   deg==0            -> out = ctx
//   has_nbr           -> out = (1-s)*f + s*mlp_b([f,f])   (w1 halves pre-added)
//   deg>0 && !has_nbr -> append node to alist (handled by k_brancha)
__global__ __launch_bounds__(256)
void k_gather_mlp(const unsigned short* __restrict__ bucket,
                  const int* __restrict__ off, const float* __restrict__ rel,
                  const float* __restrict__ ctx,
                  const float* __restrict__ w1, const float* __restrict__ b1,
                  const float* __restrict__ w2, const float* __restrict__ b2,
                  const float* __restrict__ strength,
                  float* __restrict__ out,
                  int* __restrict__ alist, int* __restrict__ alcnt, int N) {
    __shared__ float w1e[DD * DD];   // [k][j] = w1[j][k] + w1[j][k+64]
    __shared__ float w2t[DD * DD];   // [k][j] = w2[j][k]
    __shared__ float b1s[DD], b2s[DD], ctx_s[DD];

    for (int i = threadIdx.x; i < DD * DD; i += blockDim.x) {
        int j = i >> 6, k = i & 63;
        w1e[k * DD + j] = w1[j * 2 * DD + k] + w1[j * 2 * DD + DD + k];
        w2t[k * DD + j] = w2[j * DD + k];
    }
    if (threadIdx.x < DD) {
        b1s[threadIdx.x]   = b1[threadIdx.x];
        b2s[threadIdx.x]   = b2[threadIdx.x];
        ctx_s[threadIdx.x] = ctx[threadIdx.x];
    }
    __syncthreads();

    float sc = fminf(fmaxf(strength[0], 0.f), 0.3f);

    int lane = threadIdx.x & 63;
    int w    = threadIdx.x >> 6;
    int wpb  = blockDim.x >> 6;
    int stride = gridDim.x * wpb;
    for (int n = blockIdx.x * wpb + w; n < N; n += stride) {
        int o0 = off[n], o1 = off[n + 1];
        int dg = o1 - o0;
        if (dg == 0) { out[n * DD + lane] = ctx_s[lane]; continue; }

        float f = 0.f;
        int self_cnt = 0;
        int i = o0;
        for (; i + 4 <= o1; i += 4) {
            unsigned short e0 = bucket[i],     e1 = bucket[i + 1];
            unsigned short e2 = bucket[i + 2], e3 = bucket[i + 3];
            f += rel[(e0 & 0x7fff) * DD + lane];
            f += rel[(e1 & 0x7fff) * DD + lane];
            f += rel[(e2 & 0x7fff) * DD + lane];
            f += rel[(e3 & 0x7fff) * DD + lane];
            self_cnt += (e0 >> 15) + (e1 >> 15) + (e2 >> 15) + (e3 >> 15);
        }
        for (; i < o1; ++i) {
            unsigned short e = bucket[i];
            f += rel[(e & 0x7fff) * DD + lane];
            self_cnt += e >> 15;
        }
        f /= (float)dg;

        if (self_cnt == dg) {            // all incidences are self-loops
            if (lane == 0) { int p = atomicAdd(alcnt, 1); alist[p] = n; }
            continue;
        }
        // MLP-b on [f,f]
        float h = b1s[lane];
        #pragma unroll 8
        for (int k = 0; k < DD; ++k)
            h = fmaf(__shfl(f, k), w1e[k * DD + lane], h);
        h = fmaxf(h, 0.f);
        float o = b2s[lane];
        #pragma unroll 8
        for (int k = 0; k < DD; ++k)
            o = fmaf(__shfl(h, k), w2t[k * DD + lane], o);
        out[n * DD + lane] = (1.f - sc) * f + sc * o;
    }
}

// ---------------------------------------------------------------------------
// Rare branch-a nodes (deg>0, only self-loop edges): out = (1-s)f + s*mlp_a([f,ctx])
__global__ __launch_bounds__(256)
void k_brancha(const unsigned short* __restrict__ bucket,
               const int* __restrict__ off, const float* __restrict__ rel,
               const float* __restrict__ ctx,
               const float* __restrict__ w1, const float* __restrict__ b1,
               const float* __restrict__ w2, const float* __restrict__ b2,
               const float* __restrict__ strength,
               float* __restrict__ out,
               const int* __restrict__ alist, const int* __restrict__ alcnt) {
    int count = *alcnt;
    if (count == 0) return;
    float sc = fminf(fmaxf(strength[0], 0.f), 0.3f);
    int lane = threadIdx.x & 63;
    int w    = threadIdx.x >> 6;
    int wpb  = blockDim.x >> 6;
    float c = ctx[lane];
    for (int idx = w; idx < count; idx += wpb) {
        int n = alist[idx];
        int o0 = off[n], o1 = off[n + 1];
        int dg = o1 - o0;
        float f = 0.f;
        for (int i = o0; i < o1; ++i)
            f += rel[(bucket[i] & 0x7fff) * DD + lane];
        f /= (float)dg;
        // layer 1: x = [f, ctx]
        float h = b1[lane];
        for (int k = 0; k < DD; ++k)
            h = fmaf(__shfl(f, k), w1[lane * 2 * DD + k], h);
        for (int k = 0; k < DD; ++k)
            h = fmaf(__shfl(c, k), w1[lane * 2 * DD + DD + k], h);
        h = fmaxf(h, 0.f);
        float o = b2[lane];
        for (int k = 0; k < DD; ++k)
            o = fmaf(__shfl(h, k), w2[lane * DD + k], o);
        out[n * DD + lane] = (1.f - sc) * f + sc * o;
    }
}

// ---------------------------------------------------------------------------
extern "C" void kernel_launch(void* const* d_in, const int* in_sizes, int n_in,
                              void* d_out, int out_size, void* d_ws, size_t ws_size,
                              hipStream_t stream) {
    const int*   edge_index = (const int*)d_in[0];     // [2, E]
    const int*   etype      = (const int*)d_in[1];     // [E]
    const float* rel        = (const float*)d_in[2];   // [R, 64]
    const float* w1a        = (const float*)d_in[3];
    const float* b1a        = (const float*)d_in[4];
    const float* w2a        = (const float*)d_in[5];
    const float* b2a        = (const float*)d_in[6];
    const float* w1b        = (const float*)d_in[7];
    const float* b1b        = (const float*)d_in[8];
    const float* w2b        = (const float*)d_in[9];
    const float* b2b        = (const float*)d_in[10];
    const float* strength   = (const float*)d_in[11];

    int E = in_sizes[0] / 2;
    int R = in_sizes[2] / DD;
    int N = out_size / DD;

    float* out = (float*)d_out;
    char*  ws  = (char*)d_ws;

    // workspace layout (ints are 4B-aligned; bucket u16 last)
    int*   cnt   = (int*)ws;                  // N
    int*   alcnt = cnt + N;                   // 1
    int*   off   = alcnt + 1;                 // N+1
    int*   cur   = off + N + 1;               // N
    float* ctx   = (float*)(cur + N);         // 64
    int*   alist = (int*)(ctx + DD);          // N (paranoid upper bound)
    unsigned short* bucket = (unsigned short*)(alist + N);   // 2E

    // zero cnt + alcnt in one shot
    hipMemsetAsync(ws, 0, (size_t)(N + 1) * sizeof(int), stream);

    k_relctx<<<1, 512, 0, stream>>>(rel, R, ctx);

    const int* src = edge_index;
    const int* dst = edge_index + E;
    k_count<<<2048, 256, 0, stream>>>(src, dst, cnt, E);
    k_scan<<<1, 1024, 0, stream>>>(cnt, off, cur, N);
    k_place<<<2048, 256, 0, stream>>>(src, dst, etype, cur, bucket, E);

    k_gather_mlp<<<1024, 256, 0, stream>>>(bucket, off, rel, ctx,
                                           w1b, b1b, w2b, b2b, strength,
                                           out, alist, alcnt, N);
    k_brancha<<<1, 256, 0, stream>>>(bucket, off, rel, ctx,
                                     w1a, b1a, w2a, b2a, strength,
                                     out, alist, alcnt);
}